// Round 2
// baseline (944.621 us; speedup 1.0000x reference)
//
#include <hip/hip_runtime.h>
#include <hip/hip_bf16.h>

typedef __bf16 bf16;
typedef bf16  bf16x8 __attribute__((ext_vector_type(8)));
typedef float f32x4  __attribute__((ext_vector_type(4)));

#define NFRAGS    44      // 28 (W1, K padded to 224) + 8 (W2) + 8 (W3)
#define H_STRIDE  72      // 16B-aligned row stride for H tiles, breaks 64-stride conflicts
#define TILE_EDGES 128    // per block-tile: 4 waves x 32 edges
#define GRID_BLOCKS 512   // 2 per CU (LDS-limited), grid-stride over 12500 tiles

// load 8 consecutive f32 and round to a bf16x8 MFMA fragment
__device__ inline bf16x8 cvt8(const float* __restrict__ p) {
    f32x4 lo = *(const f32x4*)p;
    f32x4 hi = *(const f32x4*)(p + 4);
    bf16x8 r;
    #pragma unroll
    for (int j = 0; j < 4; ++j) { r[j] = (bf16)lo[j]; r[j + 4] = (bf16)hi[j]; }
    return r;
}

__global__ __launch_bounds__(256, 2)
void allegro_kernel(const float* __restrict__ edge_feats,
                    const float* __restrict__ node_feats,
                    const int*  __restrict__ edge_index,
                    const float* __restrict__ edge_rbf,
                    const float* __restrict__ W1, const float* __restrict__ b1,
                    const float* __restrict__ W2, const float* __restrict__ b2,
                    const float* __restrict__ W3, const float* __restrict__ b3,
                    const float* __restrict__ ln_g, const float* __restrict__ ln_b,
                    float* __restrict__ out,
                    int n_edges)
{
    // B-fragments of all 3 weight matrices, pre-swizzled into MFMA operand order:
    // frag f, lane l -> 8 bf16 = B[k = 32*s + (l>>4)*8 + j][n = 16*t + (l&15)]
    __shared__ bf16 fragbuf[NFRAGS * 64 * 8];       // 45056 B
    __shared__ bf16 hbuf[4][32 * H_STRIDE];         // 18432 B (per-wave private H tile)

    const int tid  = threadIdx.x;
    const int wave = tid >> 6;
    const int lane = tid & 63;
    const int m    = lane & 15;      // A-operand row within 16-tile / C col
    const int half = lane >> 4;      // 0..3

    // ---- build weight fragment buffer (once per block; weights are L2-resident) ----
    for (int p = tid; p < NFRAGS * 64; p += 256) {
        int f = p >> 6, ln = p & 63;
        const float* W; int Klim, fb;
        if (f < 28)      { W = W1; Klim = 208; fb = f; }
        else if (f < 36) { W = W2; Klim = 64;  fb = f - 28; }
        else             { W = W3; Klim = 64;  fb = f - 36; }
        int s  = fb >> 2, t = fb & 3;
        int kb = 32 * s + ((ln >> 4) << 3);
        int n  = 16 * t + (ln & 15);
        bf16x8 v;
        #pragma unroll
        for (int j = 0; j < 8; ++j) {
            int k = kb + j;
            v[j] = (k < Klim) ? (bf16)W[(size_t)k * 64 + n] : (bf16)0.0f;
        }
        *(bf16x8*)&fragbuf[(size_t)p * 8] = v;
    }
    __syncthreads();

    // per-lane epilogue constants (col = 16*t + m)
    float b1f[4], b2f[4], b3f[4], gf[4], btf[4];
    #pragma unroll
    for (int t = 0; t < 4; ++t) {
        b1f[t] = b1[16 * t + m];
        b2f[t] = b2[16 * t + m];
        b3f[t] = b3[16 * t + m];
        gf[t]  = ln_g[16 * t + m];
        btf[t] = ln_b[16 * t + m];
    }

    bf16x8 az;
    #pragma unroll
    for (int j = 0; j < 8; ++j) az[j] = (bf16)0.0f;

    const int n_tiles = n_edges / TILE_EDGES;
    bf16* hrow = &hbuf[wave][0];

    for (int tb = blockIdx.x; tb < n_tiles; tb += gridDim.x) {
        const int e0 = tb * TILE_EDGES + wave * 32;
        const int eA = e0 + m;          // A-row edge, m-tile 0
        const int eB = e0 + 16 + m;     // A-row edge, m-tile 1
        const int irA = edge_index[eA], icA = edge_index[n_edges + eA];
        const int irB = edge_index[eB], icB = edge_index[n_edges + eB];

        // ---------------- GEMM1: [32 x 224] @ [224 x 64] ----------------
        f32x4 acc[2][4] = {};
        #pragma unroll
        for (int s = 0; s < 7; ++s) {
            int kb = 32 * s + half * 8;
            bf16x8 a0, a1;
            if (kb < 64) {
                a0 = cvt8(edge_feats + (size_t)eA * 64 + kb);
                a1 = cvt8(edge_feats + (size_t)eB * 64 + kb);
            } else if (kb < 128) {
                a0 = cvt8(node_feats + (size_t)irA * 64 + (kb - 64));
                a1 = cvt8(node_feats + (size_t)irB * 64 + (kb - 64));
            } else if (kb < 192) {
                a0 = cvt8(node_feats + (size_t)icA * 64 + (kb - 128));
                a1 = cvt8(node_feats + (size_t)icB * 64 + (kb - 128));
            } else if (kb < 208) {
                a0 = cvt8(edge_rbf + (size_t)eA * 16 + (kb - 192));
                a1 = cvt8(edge_rbf + (size_t)eB * 16 + (kb - 192));
            } else {
                a0 = az; a1 = az;
            }
            #pragma unroll
            for (int t = 0; t < 4; ++t) {
                bf16x8 b = *(const bf16x8*)&fragbuf[((s * 4 + t) * 64 + lane) * 8];
                acc[0][t] = __builtin_amdgcn_mfma_f32_16x16x32_bf16(a0, b, acc[0][t], 0, 0, 0);
                acc[1][t] = __builtin_amdgcn_mfma_f32_16x16x32_bf16(a1, b, acc[1][t], 0, 0, 0);
            }
        }
        // epilogue 1: bias + silu -> H (C-layout: row = half*4+r, col = 16t+m)
        #pragma unroll
        for (int mt = 0; mt < 2; ++mt)
            #pragma unroll
            for (int t = 0; t < 4; ++t)
                #pragma unroll
                for (int r = 0; r < 4; ++r) {
                    float v = acc[mt][t][r] + b1f[t];
                    v = v / (1.0f + __expf(-v));
                    hrow[(mt * 16 + half * 4 + r) * H_STRIDE + 16 * t + m] = (bf16)v;
                }
        asm volatile("" ::: "memory");   // compiler fence: H writes before A reads

        // ---------------- GEMM2: [32 x 64] @ [64 x 64] ----------------
        f32x4 acc2[2][4] = {};
        #pragma unroll
        for (int s = 0; s < 2; ++s) {
            bf16x8 a0 = *(const bf16x8*)&hrow[(m)      * H_STRIDE + 32 * s + half * 8];
            bf16x8 a1 = *(const bf16x8*)&hrow[(16 + m) * H_STRIDE + 32 * s + half * 8];
            #pragma unroll
            for (int t = 0; t < 4; ++t) {
                bf16x8 b = *(const bf16x8*)&fragbuf[((28 + s * 4 + t) * 64 + lane) * 8];
                acc2[0][t] = __builtin_amdgcn_mfma_f32_16x16x32_bf16(a0, b, acc2[0][t], 0, 0, 0);
                acc2[1][t] = __builtin_amdgcn_mfma_f32_16x16x32_bf16(a1, b, acc2[1][t], 0, 0, 0);
            }
        }
        asm volatile("" ::: "memory");   // A reads before H overwrite
        #pragma unroll
        for (int mt = 0; mt < 2; ++mt)
            #pragma unroll
            for (int t = 0; t < 4; ++t)
                #pragma unroll
                for (int r = 0; r < 4; ++r) {
                    float v = acc2[mt][t][r] + b2f[t];
                    v = v / (1.0f + __expf(-v));
                    hrow[(mt * 16 + half * 4 + r) * H_STRIDE + 16 * t + m] = (bf16)v;
                }
        asm volatile("" ::: "memory");

        // ---------------- GEMM3: [32 x 64] @ [64 x 64] ----------------
        f32x4 acc3[2][4] = {};
        #pragma unroll
        for (int s = 0; s < 2; ++s) {
            bf16x8 a0 = *(const bf16x8*)&hrow[(m)      * H_STRIDE + 32 * s + half * 8];
            bf16x8 a1 = *(const bf16x8*)&hrow[(16 + m) * H_STRIDE + 32 * s + half * 8];
            #pragma unroll
            for (int t = 0; t < 4; ++t) {
                bf16x8 b = *(const bf16x8*)&fragbuf[((36 + s * 4 + t) * 64 + lane) * 8];
                acc3[0][t] = __builtin_amdgcn_mfma_f32_16x16x32_bf16(a0, b, acc3[0][t], 0, 0, 0);
                acc3[1][t] = __builtin_amdgcn_mfma_f32_16x16x32_bf16(a1, b, acc3[1][t], 0, 0, 0);
            }
        }

        // epilogue 3: bias + residual (f32), then LayerNorm per row + store
        float y[2][4][4];
        #pragma unroll
        for (int mt = 0; mt < 2; ++mt)
            #pragma unroll
            for (int t = 0; t < 4; ++t)
                #pragma unroll
                for (int r = 0; r < 4; ++r) {
                    int row = e0 + mt * 16 + half * 4 + r;
                    float ef = edge_feats[(size_t)row * 64 + 16 * t + m];
                    y[mt][t][r] = acc3[mt][t][r] + b3f[t] + ef;
                }

        #pragma unroll
        for (int mt = 0; mt < 2; ++mt)
            #pragma unroll
            for (int r = 0; r < 4; ++r) {
                float s1 = y[mt][0][r] + y[mt][1][r] + y[mt][2][r] + y[mt][3][r];
                float s2 = y[mt][0][r] * y[mt][0][r] + y[mt][1][r] * y[mt][1][r]
                         + y[mt][2][r] * y[mt][2][r] + y[mt][3][r] * y[mt][3][r];
                // 64 values of this row live in the 16 lanes sharing `half` (4 per lane)
                #pragma unroll
                for (int mask = 1; mask < 16; mask <<= 1) {
                    s1 += __shfl_xor(s1, mask);
                    s2 += __shfl_xor(s2, mask);
                }
                float mu  = s1 * (1.0f / 64.0f);
                float var = s2 * (1.0f / 64.0f) - mu * mu;
                float rs  = rsqrtf(var + 1e-5f);
                int row = e0 + mt * 16 + half * 4 + r;
                #pragma unroll
                for (int t = 0; t < 4; ++t) {
                    float o = (y[mt][t][r] - mu) * rs * gf[t] + btf[t];
                    out[(size_t)row * 64 + 16 * t + m] = o;
                }
            }
    }
}

extern "C" void kernel_launch(void* const* d_in, const int* in_sizes, int n_in,
                              void* d_out, int out_size, void* d_ws, size_t ws_size,
                              hipStream_t stream) {
    const float* edge_feats = (const float*)d_in[0];
    const float* node_feats = (const float*)d_in[1];
    const int*   edge_index = (const int*)  d_in[2];
    const float* edge_rbf   = (const float*)d_in[3];
    const float* W1 = (const float*)d_in[4];
    const float* b1 = (const float*)d_in[5];
    const float* W2 = (const float*)d_in[6];
    const float* b2 = (const float*)d_in[7];
    const float* W3 = (const float*)d_in[8];
    const float* b3 = (const float*)d_in[9];
    const float* g  = (const float*)d_in[10];
    const float* be = (const float*)d_in[11];
    const int E = in_sizes[0] / 64;

    allegro_kernel<<<dim3(GRID_BLOCKS), dim3(256), 0, stream>>>(
        edge_feats, node_feats, edge_index, edge_rbf,
        W1, b1, W2, b2, W3, b3, g, be, (float*)d_out, E);
}